// Round 6
// baseline (874.393 us; speedup 1.0000x reference)
//
#include <hip/hip_runtime.h>
#include <hip/hip_bf16.h>
#include <math.h>
#include <stdint.h>

// ---------------------------------------------------------------------------
// SwinTransformerBlock1D.  Inputs fp32, output fp32, internal bf16 MFMA.
// B=4 L=8192 DIM=512 HEADS=8 WIN=256 HEAD_DIM=64 HID=2048.
// R12: R11's coalesced staging kept (FETCH 165->50MB, verified), spill
//     removed.  R11 diagnosis: 8 resident waves => 256 regs/wave; acc=128
//     leaves arch<=128; R11's addressing pushed demand past it -> allocator
//     capped at 112 + scratch spill (WRITE 85->319MB, VALU 8->22%).
//     Fix: fragment live-set cut 64->48 VGPR: read all 4 B-subtiles once
//     (G0), sweep A 2 subtiles/group (G0..G3), 16 MFMA/group.  G3 orders
//     ds_read A6-7 -> lgkmcnt(0) -> barrier -> stage A(t+2) so the overwrite
//     can't race other waves' reads.  Counted vmcnt(8) boundary unchanged.
// MFMA fragment layouts (m89/m91-verified): A[m=lane&15][k=quad*8+j],
// B[n=lane&15][k=quad*8+j], D[row=quad*4+r][col=lane&15].
// ---------------------------------------------------------------------------

typedef __attribute__((ext_vector_type(8))) __bf16 bf16x8;
typedef __attribute__((ext_vector_type(4))) __bf16 bf16x4;
typedef __attribute__((ext_vector_type(4))) float  f32x4;

#define NTOK  32768
#define DIMC  512
#define HEADS 8
#define WIN   256
#define HD    64
#define HIDC  2048
#define LDP   40   // padded LDS k-stride for 64-tile attention kernels

// async global->LDS, 16B per lane; LDS dest = wave-uniform base + lane*16B
__device__ __forceinline__ void gld16(const __bf16* g, __bf16* l)
{
    __builtin_amdgcn_global_load_lds(
        (const __attribute__((address_space(1))) void*)g,
        (__attribute__((address_space(3))) void*)l, 16, 0, 0);
}

// asm ds_read_b128 at base VGPR address + literal byte offset.
#define DSR(dst, base, off) \
    asm volatile("ds_read_b128 %0, %1 offset:" off : "=v"(dst) : "v"(base))

// ---------------- 256x256 GEMM, 4-group, 2-tile-deep pipeline --------------
// A (MxK row-major), Bt (NxK row-major).  512 threads = 8 waves (wm=wave>>2,
// wn=wave&3); wave computes 128x64 of C (8 m-subtiles x 4 n-subtiles).
// LDS per operand per buffer: 256 rows x 64 k, byte(row,c) = row*128 +
// (c^(row&7))*16  (c = 16B k-chunk).  Staged as 8-row slabs, 1KB contiguous
// per gld16 (8 full 128B lines), source chunk pre-swizzled (lane&7)^(lane>>3).
// Fragment (sub,ks) read at base_ks + sub*2048, base_ks = l16*128 +
// (((ks*4+quad)^(l16&7))<<4)  (bank-conflict-free, counter-verified R11).
// Groups: G0 reads B0-3+A0-1 (12 ds_read), mfma A01xB; G1 reads A2-3, mfma;
// G2 reads A4-5 + stages B(t+2); G3 reads A6-7 (lgkm-before-barrier) +
// stages A(t+2); boundary s_waitcnt vmcnt(8).  MODE 0:+bias 1:+res 2:gelu.
template<int MODE, int OUTF>
__global__ __launch_bounds__(512, 2) void gemm256(
    const __bf16* __restrict__ A, int lda,
    const __bf16* __restrict__ Bt, int ldb,
    const float* __restrict__ bias,
    const void* __restrict__ res, int res_f32,
    void* __restrict__ C, int ldc, int K,
    int nM, int nN)
{
    __shared__ __bf16 lds[2][2][16384];   // [buf][A=0/B=1], 32KB each
    const int tid  = threadIdx.x;
    const int wave = tid >> 6, lane = tid & 63;
    const int quad = lane >> 4, l16 = lane & 15;
    const int wm = wave >> 2, wn = wave & 3;   // 2x4 wave grid

    // XCD swizzle: id%8 = XCD; each XCD owns nM/8 consecutive m-tiles.
    const int id  = blockIdx.x;
    const int xcd = id & 7;
    const int lid = id >> 3;
    const int mq  = lid / nN;
    const int mt  = xcd * (nM >> 3) + mq;
    const int nt  = lid - mq * nN;
    const int m0 = mt * 256, n0 = nt * 256;

    // staging: wave w stages rows w*32+j*8 .. +7 (j=0..3) of A and B.
    // lane -> row +(lane>>3), source 16B chunk (lane&7)^(lane>>3).
    const int lr = lane >> 3;                  // 0..7
    const int lc = (lane & 7) ^ lr;            // swizzled source chunk
    int aoff[4], boff[4];
    #pragma unroll
    for (int j = 0; j < 4; j++) {
        const int row = wave * 32 + j * 8 + lr;
        aoff[j] = (m0 + row) * lda + lc * 8;
        boff[j] = (n0 + row) * ldb + lc * 8;
    }

    // ds_read base addresses (byte), one per (operand, ks); buf adds 65536.
    const uint32_t lds0 =
        (uint32_t)(uintptr_t)(__attribute__((address_space(3))) void*)&lds[0][0][0];
    const int e = l16 & 7;
    const uint32_t rdA0 = lds0 + wm * 16384 + l16 * 128 + (((0 + quad) ^ e) << 4);
    const uint32_t rdA1 = lds0 + wm * 16384 + l16 * 128 + (((4 + quad) ^ e) << 4);
    const uint32_t rdB0 = lds0 + 32768 + wn * 8192 + l16 * 128 + (((0 + quad) ^ e) << 4);
    const uint32_t rdB1 = lds0 + 32768 + wn * 8192 + l16 * 128 + (((4 + quad) ^ e) << 4);

    f32x4 acc[8][4] = {};
    bf16x8 rA[2][2], rB[4][2];

    const int ntk = K >> 6;

    // prologue: stage tile 0 -> buf0, tile 1 -> buf1; wait for tile 0 only.
    #pragma unroll
    for (int j = 0; j < 4; j++) {
        gld16(A  + aoff[j], &lds[0][0][wave * 2048 + j * 512]);
        gld16(Bt + boff[j], &lds[0][1][wave * 2048 + j * 512]);
    }
    #pragma unroll
    for (int j = 0; j < 4; j++) {
        gld16(A  + aoff[j] + 64, &lds[1][0][wave * 2048 + j * 512]);
        gld16(Bt + boff[j] + 64, &lds[1][1][wave * 2048 + j * 512]);
    }
    asm volatile("s_waitcnt vmcnt(8)");
    __builtin_amdgcn_s_barrier();

    for (int t = 0; t < ntk; ++t) {
        const int buf = t & 1;
        const uint32_t bo = (uint32_t)buf * 65536u;
        const uint32_t aA0 = rdA0 + bo, aA1 = rdA1 + bo;
        const uint32_t bB0 = rdB0 + bo, bB1 = rdB1 + bo;
        const bool pf = (t + 2 < ntk);
        const int kn = (t + 2) << 6;

        // ---- G0: ds_read B n0-3 + A m0-1; mfma m0-1 x n0-3
        DSR(rB[0][0], bB0, "0");    DSR(rB[0][1], bB1, "0");
        DSR(rB[1][0], bB0, "2048"); DSR(rB[1][1], bB1, "2048");
        DSR(rB[2][0], bB0, "4096"); DSR(rB[2][1], bB1, "4096");
        DSR(rB[3][0], bB0, "6144"); DSR(rB[3][1], bB1, "6144");
        DSR(rA[0][0], aA0, "0");    DSR(rA[0][1], aA1, "0");
        DSR(rA[1][0], aA0, "2048"); DSR(rA[1][1], aA1, "2048");
        __builtin_amdgcn_s_barrier();
        asm volatile("s_waitcnt lgkmcnt(0)");
        __builtin_amdgcn_sched_barrier(0);
        __builtin_amdgcn_s_setprio(1);
        #pragma unroll
        for (int ii = 0; ii < 2; ii++)
            #pragma unroll
            for (int j = 0; j < 4; j++)
                #pragma unroll
                for (int ks = 0; ks < 2; ks++)
                    acc[ii][j] = __builtin_amdgcn_mfma_f32_16x16x32_bf16(
                        rA[ii][ks], rB[j][ks], acc[ii][j], 0, 0, 0);
        __builtin_amdgcn_s_setprio(0);
        __builtin_amdgcn_s_barrier();

        // ---- G1: ds_read A m2-3; mfma m2-3 x n0-3
        DSR(rA[0][0], aA0, "4096"); DSR(rA[0][1], aA1, "4096");
        DSR(rA[1][0], aA0, "6144"); DSR(rA[1][1], aA1, "6144");
        __builtin_amdgcn_s_barrier();
        asm volatile("s_waitcnt lgkmcnt(0)");
        __builtin_amdgcn_sched_barrier(0);
        __builtin_amdgcn_s_setprio(1);
        #pragma unroll
        for (int ii = 0; ii < 2; ii++)
            #pragma unroll
            for (int j = 0; j < 4; j++)
                #pragma unroll
                for (int ks = 0; ks < 2; ks++)
                    acc[2 + ii][j] = __builtin_amdgcn_mfma_f32_16x16x32_bf16(
                        rA[ii][ks], rB[j][ks], acc[2 + ii][j], 0, 0, 0);
        __builtin_amdgcn_s_setprio(0);
        __builtin_amdgcn_s_barrier();

        // ---- G2: ds_read A m4-5; stage B(t+2) into this buf's B-half
        //      (B(t) regs were loaded in G0; overwrite is barrier-separated)
        DSR(rA[0][0], aA0, "8192");  DSR(rA[0][1], aA1, "8192");
        DSR(rA[1][0], aA0, "10240"); DSR(rA[1][1], aA1, "10240");
        if (pf) {
            #pragma unroll
            for (int j = 0; j < 4; j++)
                gld16(Bt + boff[j] + kn, &lds[buf][1][wave * 2048 + j * 512]);
        }
        __builtin_amdgcn_s_barrier();
        asm volatile("s_waitcnt lgkmcnt(0)");
        __builtin_amdgcn_sched_barrier(0);
        __builtin_amdgcn_s_setprio(1);
        #pragma unroll
        for (int ii = 0; ii < 2; ii++)
            #pragma unroll
            for (int j = 0; j < 4; j++)
                #pragma unroll
                for (int ks = 0; ks < 2; ks++)
                    acc[4 + ii][j] = __builtin_amdgcn_mfma_f32_16x16x32_bf16(
                        rA[ii][ks], rB[j][ks], acc[4 + ii][j], 0, 0, 0);
        __builtin_amdgcn_s_setprio(0);
        __builtin_amdgcn_s_barrier();

        // ---- G3: ds_read A m6-7 -> lgkmcnt(0) BEFORE barrier (so the
        //      A-stage below can't race any wave's A-reads), then stage
        //      A(t+2); mfma m6-7 x n0-3; counted boundary wait
        DSR(rA[0][0], aA0, "12288"); DSR(rA[0][1], aA1, "12288");
        DSR(rA[1][0], aA0, "14336"); DSR(rA[1][1], aA1, "14336");
        asm volatile("s_waitcnt lgkmcnt(0)");
        __builtin_amdgcn_s_barrier();
        if (pf) {
            #pragma unroll
            for (int j = 0; j < 4; j++)
                gld16(A + aoff[j] + kn, &lds[buf][0][wave * 2048 + j * 512]);
        }
        __builtin_amdgcn_sched_barrier(0);
        __builtin_amdgcn_s_setprio(1);
        #pragma unroll
        for (int ii = 0; ii < 2; ii++)
            #pragma unroll
            for (int j = 0; j < 4; j++)
                #pragma unroll
                for (int ks = 0; ks < 2; ks++)
                    acc[6 + ii][j] = __builtin_amdgcn_mfma_f32_16x16x32_bf16(
                        rA[ii][ks], rB[j][ks], acc[6 + ii][j], 0, 0, 0);
        __builtin_amdgcn_s_setprio(0);
        // need A(t+1),B(t+1) landed; t+2's 8 loads may stay in flight.
        if (pf)                  asm volatile("s_waitcnt vmcnt(8)");
        else if (t + 1 < ntk)    asm volatile("s_waitcnt vmcnt(0)");
        __builtin_amdgcn_s_barrier();
    }

    // epilogue: wave writes rows m0+wm*128+i*16+quad*4+r, cols n0+wn*64+j*16+l16
    #pragma unroll
    for (int j = 0; j < 4; j++) {
        const int col = n0 + wn * 64 + j * 16 + l16;
        const float bv = bias[col];
        #pragma unroll
        for (int i = 0; i < 8; i++) {
            #pragma unroll
            for (int r = 0; r < 4; r++) {
                const int row = m0 + wm * 128 + i * 16 + quad * 4 + r;
                const size_t off = (size_t)row * ldc + col;
                float v = acc[i][j][r] + bv;
                if (MODE == 2) v = 0.5f * v * (1.0f + erff(v * 0.70710678118654752f));
                if (MODE == 1)
                    v += res_f32 ? ((const float*)res)[off]
                                 : (float)((const __bf16*)res)[off];
                if (OUTF) ((float*)C)[off] = v;
                else      ((__bf16*)C)[off] = (__bf16)v;
            }
        }
    }
}

// ---------------- fused QK^T * scale + rpb bias + softmax -> P -------------
// One block: 64 q-rows x full 256 k for one (window,head).  4 waves, each
// wave owns 16 q-rows (wave*16 + quad*4 + r), 16 col-blocks of 16.
__global__ __launch_bounds__(256) void qk_softmax(
    const __bf16* __restrict__ qkvb, const float* __restrict__ rpb,
    __bf16* __restrict__ Sc, int bh_base)
{
    __shared__ __align__(16) __bf16 Qs[64 * 72];
    __shared__ __align__(16) __bf16 Ks[256 * 72];
    __shared__ float rpbs[320];
    const int bhl = blockIdx.y;
    const int bh  = bh_base + bhl;
    const int bw = bh >> 3, head = bh & 7;
    const int m0 = blockIdx.x * 64;
    const int tid = threadIdx.x;
    const __bf16* qb = qkvb + (size_t)bw * WIN * 1536 + head * HD;

    {   // stage Q (64x64) and K (256x64), rows of 64 elems = 8 x bf16x8
        const int row = tid >> 3, l8 = (tid & 7) * 8;
        #pragma unroll
        for (int p = 0; p < 2; p++) {
            const int r = p * 32 + row;
            *(bf16x8*)(Qs + r * 72 + l8) =
                *(const bf16x8*)(qb + (size_t)(m0 + r) * 1536 + l8);
        }
        #pragma unroll
        for (int p = 0; p < 8; p++) {
            const int r = p * 32 + row;
            *(bf16x8*)(Ks + r * 72 + l8) =
                *(const bf16x8*)(qb + 512 + (size_t)r * 1536 + l8);
        }
        // rpb slice: bias(i,j) = rpb[i-j+255]; i-j+255-m0 in [0,318]
        rpbs[tid] = rpb[(size_t)(m0 + tid) * HEADS + head];
        if (tid < 63) rpbs[256 + tid] = rpb[(size_t)(m0 + 256 + tid) * HEADS + head];
    }
    __syncthreads();

    const int wave = tid >> 6, lane = tid & 63;
    const int quad = lane >> 4, l16 = lane & 15;
    bf16x8 af[2];
    #pragma unroll
    for (int ks = 0; ks < 2; ks++)
        af[ks] = *(const bf16x8*)(Qs + (wave * 16 + l16) * 72 + ks * 32 + quad * 8);

    f32x4 acc[16];
    #pragma unroll
    for (int nb = 0; nb < 16; nb++) acc[nb] = (f32x4){0.f, 0.f, 0.f, 0.f};
    #pragma unroll
    for (int nb = 0; nb < 16; nb++) {
        #pragma unroll
        for (int ks = 0; ks < 2; ks++) {
            bf16x8 bf = *(const bf16x8*)(Ks + (nb * 16 + l16) * 72 + ks * 32 + quad * 8);
            acc[nb] = __builtin_amdgcn_mfma_f32_16x16x32_bf16(af[ks], bf, acc[nb], 0, 0, 0);
        }
    }
    // scale + bias:  row li = wave*16+quad*4+r, col j = nb*16+l16
    #pragma unroll
    for (int nb = 0; nb < 16; nb++)
        #pragma unroll
        for (int r = 0; r < 4; r++) {
            const int li = wave * 16 + quad * 4 + r;
            acc[nb][r] = acc[nb][r] * 0.125f + rpbs[li - nb * 16 - l16 + 255];
        }
    // softmax per row r: reduce over nb (in-lane) then l16 (shfl within quad)
    __bf16* Sb = Sc + (size_t)bhl * (WIN * WIN);
    #pragma unroll
    for (int r = 0; r < 4; r++) {
        float m = -1e30f;
        #pragma unroll
        for (int nb = 0; nb < 16; nb++) m = fmaxf(m, acc[nb][r]);
        #pragma unroll
        for (int msk = 1; msk < 16; msk <<= 1) m = fmaxf(m, __shfl_xor(m, msk));
        float s = 0.f;
        #pragma unroll
        for (int nb = 0; nb < 16; nb++) { acc[nb][r] = __expf(acc[nb][r] - m); s += acc[nb][r]; }
        #pragma unroll
        for (int msk = 1; msk < 16; msk <<= 1) s += __shfl_xor(s, msk);
        const float inv = 1.0f / s;
        const int i = m0 + wave * 16 + quad * 4 + r;
        #pragma unroll
        for (int nb = 0; nb < 16; nb++)
            Sb[(size_t)i * WIN + nb * 16 + l16] = (__bf16)(acc[nb][r] * inv);
    }
}

// ---------------- 64x64 MFMA tile helper (pv) ------------------------------
__device__ __forceinline__ void mfma_tile64(
    const __bf16* __restrict__ A, int lda, int m0,
    const __bf16* __restrict__ Bt, int ldb, int n0,
    int K, f32x4* acc, __bf16* As, __bf16* Bs)
{
    const int tid  = threadIdx.x;
    const int wave = tid >> 6;
    const int lane = tid & 63;
    const int quad = lane >> 4;
    const int l16  = lane & 15;
    const int lrow = tid >> 2;          // 0..63
    const int lcol = (tid & 3) << 3;    // 0,8,16,24
    const __bf16* ap = A  + (size_t)(m0 + lrow) * lda + lcol;
    const __bf16* bp = Bt + (size_t)(n0 + lrow) * ldb + lcol;
    for (int k0 = 0; k0 < K; k0 += 32) {
        bf16x8 av = *(const bf16x8*)(ap + k0);
        bf16x8 bv = *(const bf16x8*)(bp + k0);
        __syncthreads();
        *(bf16x8*)(As + lrow * LDP + lcol) = av;
        *(bf16x8*)(Bs + lrow * LDP + lcol) = bv;
        __syncthreads();
        bf16x8 af = *(const bf16x8*)(As + (wave * 16 + l16) * LDP + (quad << 3));
        #pragma unroll
        for (int nb = 0; nb < 4; nb++) {
            bf16x8 bf = *(const bf16x8*)(Bs + (nb * 16 + l16) * LDP + (quad << 3));
            acc[nb] = __builtin_amdgcn_mfma_f32_16x16x32_bf16(af, bf, acc[nb], 0, 0, 0);
        }
    }
}

// ---------------- V^T per (window,head): Vt[d][j] = V[j][d] ----------------
__global__ __launch_bounds__(256) void vtrans(
    const __bf16* __restrict__ qkvb, __bf16* __restrict__ Vt, int bh_base)
{
    __shared__ __align__(16) __bf16 s[WIN * 72];
    const int bh = bh_base + blockIdx.x;
    const int bw = bh >> 3, head = bh & 7;
    const int tid = threadIdx.x;
    const __bf16* V = qkvb + (size_t)bw * WIN * 1536 + 1024 + head * HD;
    #pragma unroll
    for (int it = 0; it < 8; it++) {
        int idx = it * 256 + tid;
        int j = idx >> 3;
        int d0 = (idx & 7) * 8;
        *(bf16x8*)(s + j * 72 + d0) = *(const bf16x8*)(V + (size_t)j * 1536 + d0);
    }
    __syncthreads();
    __bf16* out = Vt + (size_t)blockIdx.x * (HD * WIN);
    #pragma unroll
    for (int it = 0; it < 8; it++) {
        int idx = it * 256 + tid;
        int d  = idx >> 5;
        int j0 = (idx & 31) * 8;
        bf16x8 v;
        #pragma unroll
        for (int j = 0; j < 8; j++) v[j] = s[(j0 + j) * 72 + d];
        *(bf16x8*)(out + (size_t)d * WIN + j0) = v;
    }
}

// ---------------- P@V -> attn_out ------------------------------------------
__global__ __launch_bounds__(256) void pv_gemm(
    const __bf16* __restrict__ Sc, const __bf16* __restrict__ Vt,
    __bf16* __restrict__ attnO, int bh_base)
{
    __shared__ __align__(16) __bf16 As[64 * LDP];
    __shared__ __align__(16) __bf16 Bs[64 * LDP];
    const int bhl = blockIdx.y;
    const int bh = bh_base + bhl;
    const int bw = bh >> 3, head = bh & 7;
    const int m0 = blockIdx.x * 64;
    const __bf16* P   = Sc + (size_t)bhl * (WIN * WIN);
    const __bf16* Vtb = Vt + (size_t)bhl * (HD * WIN);
    f32x4 acc[4] = {};
    mfma_tile64(P, WIN, m0, Vtb, WIN, 0, WIN, acc, As, Bs);
    const int lane = threadIdx.x & 63, wave = threadIdx.x >> 6;
    const int quad = lane >> 4, l16 = lane & 15;
    #pragma unroll
    for (int nb = 0; nb < 4; nb++) {
        const int d = nb * 16 + l16;
        #pragma unroll
        for (int r = 0; r < 4; r++) {
            const int i = m0 + wave * 16 + quad * 4 + r;
            attnO[(size_t)(bw * WIN + i) * DIMC + head * HD + d] = (__bf16)acc[nb][r];
        }
    }
}

// ---------------- LayerNorm: one wave per token ----------------------------
__global__ __launch_bounds__(256) void ln_kernel(
    const void* X, int xf,
    const float* __restrict__ g, const float* __restrict__ b,
    __bf16* O)
{
    const int tok  = blockIdx.x * 4 + (threadIdx.x >> 6);
    const int lane = threadIdx.x & 63;
    const size_t base = (size_t)tok * DIMC + lane * 8;
    float v[8];
    if (xf) {
        const float* xp = (const float*)X + base;
        f32x4 a = *(const f32x4*)xp;
        f32x4 c = *(const f32x4*)(xp + 4);
        #pragma unroll
        for (int j = 0; j < 4; j++) { v[j] = a[j]; v[4 + j] = c[j]; }
    } else {
        bf16x8 xv = *(const bf16x8*)((const __bf16*)X + base);
        #pragma unroll
        for (int j = 0; j < 8; j++) v[j] = (float)xv[j];
    }
    float s = 0.f, s2 = 0.f;
    #pragma unroll
    for (int j = 0; j < 8; j++) { s += v[j]; s2 += v[j] * v[j]; }
    #pragma unroll
    for (int off = 32; off; off >>= 1) { s += __shfl_xor(s, off); s2 += __shfl_xor(s2, off); }
    const float mean = s * (1.0f / DIMC);
    const float var  = s2 * (1.0f / DIMC) - mean * mean;
    const float rstd = rsqrtf(var + 1e-5f);
    f32x4 ga = *(const f32x4*)(g + lane * 8);
    f32x4 gc = *(const f32x4*)(g + lane * 8 + 4);
    f32x4 ba = *(const f32x4*)(b + lane * 8);
    f32x4 bc = *(const f32x4*)(b + lane * 8 + 4);
    bf16x8 ov;
    #pragma unroll
    for (int j = 0; j < 4; j++) {
        ov[j]     = (__bf16)((v[j]     - mean) * rstd * ga[j] + ba[j]);
        ov[4 + j] = (__bf16)((v[4 + j] - mean) * rstd * gc[j] + bc[j]);
    }
    *(bf16x8*)(O + base) = ov;
}

// ---------------- weight transpose+cast: fp32 KxN -> bf16 NxK --------------
__global__ __launch_bounds__(256) void wtrans(
    const float* __restrict__ W, __bf16* __restrict__ Wt, int K, int N)
{
    __shared__ __align__(16) __bf16 s[64 * 72];
    const int kb = blockIdx.y * 64, nb = blockIdx.x * 64;
    const int tid = threadIdx.x;
    #pragma unroll
    for (int it = 0; it < 2; it++) {
        int idx = it * 256 + tid;
        int lk = idx >> 3;
        int ln = (idx & 7) * 8;
        const float* wp = W + (size_t)(kb + lk) * N + nb + ln;
        f32x4 a = *(const f32x4*)wp;
        f32x4 c = *(const f32x4*)(wp + 4);
        bf16x8 v;
        #pragma unroll
        for (int j = 0; j < 4; j++) { v[j] = (__bf16)a[j]; v[4 + j] = (__bf16)c[j]; }
        *(bf16x8*)(s + lk * 72 + ln) = v;
    }
    __syncthreads();
    #pragma unroll
    for (int it = 0; it < 2; it++) {
        int idx = it * 256 + tid;
        int ln  = idx >> 3;
        int lkv = (idx & 7) * 8;
        bf16x8 v;
        #pragma unroll
        for (int j = 0; j < 8; j++) v[j] = s[(lkv + j) * 72 + ln];
        *(bf16x8*)(Wt + (size_t)(nb + ln) * K + kb + lkv) = v;
    }
}

// ---------------------------------------------------------------------------
extern "C" void kernel_launch(void* const* d_in, const int* in_sizes, int n_in,
                              void* d_out, int out_size, void* d_ws, size_t ws_size,
                              hipStream_t stream)
{
    const float* x      = (const float*)d_in[0];
    const float* n1g    = (const float*)d_in[1];
    const float* n1b    = (const float*)d_in[2];
    const float* qkv_w  = (const float*)d_in[3];
    const float* qkv_b  = (const float*)d_in[4];
    const float* rpb    = (const float*)d_in[5];
    const float* proj_w = (const float*)d_in[6];
    const float* proj_b = (const float*)d_in[7];
    const float* n2g    = (const float*)d_in[8];
    const float* n2b    = (const float*)d_in[9];
    const float* fc1_w  = (const float*)d_in[10];
    const float* fc1_b  = (const float*)d_in[11];
    const float* fc2_w  = (const float*)d_in[12];
    const float* fc2_b  = (const float*)d_in[13];
    float* out = (float*)d_out;

    // workspace layout (bytes), 216 MB peak; slots reused sequentially
    char* ws = (char*)d_ws;
    __bf16* qkvb  = (__bf16*)(ws + 0);
    __bf16* hid   = (__bf16*)(ws + 0);
    __bf16* h     = (__bf16*)(ws + 134217728);   // also Sc slot, also y/x2
    __bf16* Sc    = h;
    __bf16* y     = h;
    __bf16* attnO = (__bf16*)(ws + 167772160);
    __bf16* Vt    = (__bf16*)(ws + 201326592);
    __bf16* wq_t  = (__bf16*)(ws + 209715200);   // 1536x512
    __bf16* wp_t  = (__bf16*)(ws + 211288064);   // 512x512
    __bf16* w1_t  = (__bf16*)(ws + 211812352);   // 2048x512
    __bf16* w2_t  = (__bf16*)(ws + 213909504);   // 512x2048

    // 1) weight transposes (tiny)
    wtrans<<<dim3(1536 / 64, 512 / 64),  256, 0, stream>>>(qkv_w, wq_t, 512, 1536);
    wtrans<<<dim3(512 / 64,  512 / 64),  256, 0, stream>>>(proj_w, wp_t, 512, 512);
    wtrans<<<dim3(2048 / 64, 512 / 64),  256, 0, stream>>>(fc1_w, w1_t, 512, 2048);
    wtrans<<<dim3(512 / 64,  2048 / 64), 256, 0, stream>>>(fc2_w, w2_t, 2048, 512);

    // 2) LN1: h = LN(x)
    ln_kernel<<<NTOK / 4, 256, 0, stream>>>(x, 1, n1g, n1b, h);

    // 3) qkv = h @ qkv_w + qkv_b   (M=32768, N=1536, K=512); nM=128 nN=6
    gemm256<0, 0><<<768, 512, 0, stream>>>(
        h, DIMC, wq_t, DIMC, qkv_b, nullptr, 0, qkvb, 1536, DIMC, 128, 6);

    // 4) attention in 4 chunks of 256 (window,head) pairs
    for (int c = 0; c < 4; c++) {
        const int bh0 = c * 256;
        vtrans<<<256, 256, 0, stream>>>(qkvb, Vt, bh0);
        qk_softmax<<<dim3(4, 256), 256, 0, stream>>>(qkvb, rpb, Sc, bh0);
        pv_gemm<<<dim3(4, 256), 256, 0, stream>>>(Sc, Vt, attnO, bh0);
    }

    // 5) y = x + attnO @ proj_w + proj_b   (N=512, K=512); nM=128 nN=2
    gemm256<1, 0><<<256, 512, 0, stream>>>(
        attnO, DIMC, wp_t, DIMC, proj_b, x, 1, y, DIMC, DIMC, 128, 2);

    // 6) LN2 in place: x2 = LN(y)
    ln_kernel<<<NTOK / 4, 256, 0, stream>>>(y, 0, n2g, n2b, y);

    // 7) hid = gelu(x2 @ fc1_w + fc1_b)   (N=2048, K=512); nM=128 nN=8
    gemm256<2, 0><<<1024, 512, 0, stream>>>(
        y, DIMC, w1_t, DIMC, fc1_b, nullptr, 0, hid, HIDC, DIMC, 128, 8);

    // 8) out(fp32) = x2 + hid @ fc2_w + fc2_b  (N=512, K=2048); nM=128 nN=2
    gemm256<1, 1><<<256, 512, 0, stream>>>(
        hid, HIDC, w2_t, HIDC, fc2_b, y, 0, out, DIMC, HIDC, 128, 2);
}

// Round 7
// 680.097 us; speedup vs baseline: 1.2857x; 1.2857x over previous
//
#include <hip/hip_runtime.h>
#include <hip/hip_bf16.h>
#include <math.h>
#include <stdint.h>

// ---------------------------------------------------------------------------
// SwinTransformerBlock1D.  Inputs fp32, output fp32, internal bf16 MFMA.
// B=4 L=8192 DIM=512 HEADS=8 WIN=256 HEAD_DIM=64 HID=2048.
// R13 = R10 base (fragment-order staging, asm ds_read, counted vmcnt; the
//     cleanest measured config: 173us top, WRITE 85MB, VGPR 128) + ONE
//     change: swapped-operand MFMA + vectorized epilogue.
//     Diagnosis: epilogue was 128 scalar 2B stores/thread (65k store
//     instrs per block ~ 16k cyc issue, no overlap, 1 block/CU) -- ~8x the
//     VMEM instruction count of the whole K-loop; identical across
//     R8-R12, which is why every schedule change was null.
//     mfma(B,A) puts r=0..3 on 4 CONSECUTIVE COLUMNS of one C-row:
//     lane(quad,l16) holds C[m=i*16+l16][n=j*16+quad*4+r] -> 32x 8B
//     bf16x4 stores (16B f32x4 for fp32 out), vectorized bias/res.
// MFMA fragment layouts (m89/m91-verified): A[m=lane&15][k=quad*8+j],
// B[n=lane&15][k=quad*8+j], D[row=quad*4+r][col=lane&15].
// ---------------------------------------------------------------------------

typedef __attribute__((ext_vector_type(8))) __bf16 bf16x8;
typedef __attribute__((ext_vector_type(4))) __bf16 bf16x4;
typedef __attribute__((ext_vector_type(4))) float  f32x4;

#define NTOK  32768
#define DIMC  512
#define HEADS 8
#define WIN   256
#define HD    64
#define HIDC  2048
#define LDP   40   // padded LDS k-stride for 64-tile attention kernels

// async global->LDS, 16B per lane; LDS dest = wave-uniform base + lane*16B
__device__ __forceinline__ void gld16(const __bf16* g, __bf16* l)
{
    __builtin_amdgcn_global_load_lds(
        (const __attribute__((address_space(1))) void*)g,
        (__attribute__((address_space(3))) void*)l, 16, 0, 0);
}

// asm ds_read_b128 at base VGPR address + literal byte offset.
#define DSR(dst, base, off) \
    asm volatile("ds_read_b128 %0, %1 offset:" off : "=v"(dst) : "v"(base))

// ---------------- 256x256 GEMM, 4-phase, 2-tile-deep pipeline --------------
// A (MxK row-major), Bt (NxK row-major).  512 threads = 8 waves (wm=wave>>2,
// wn=wave&3); wave computes 128x64 of C (8 m-subtiles x 4 n-subtiles).
// LDS per buffer: A = 32 slices of 512 elems (slice S = msub*2+ks, msub
// 0..15 = 16-row group, ks = 32-k half), fragment-lane order (lane*8); B same
// over n.  Wave w stages slices S = w*4..w*4+3 of A and of B via gld16.
// Phases (C-quadrants): P0 m0-3 x n0-1, P1 m0-3 x n2-3, P2 m4-7 x n0-1,
// P3 m4-7 x n2-3.  Stage B(t+2) at P2, A(t+2) at P3; boundary vmcnt(8).
// MFMA called as mfma(B,A): acc[i][j][r] = C[i*16+l16][j*16+quad*4+r].
// MODE 0: +bias; 1: +res; 2: gelu.  OUTF 1: fp32 out.
template<int MODE, int OUTF>
__global__ __launch_bounds__(512, 2) void gemm256(
    const __bf16* __restrict__ A, int lda,
    const __bf16* __restrict__ Bt, int ldb,
    const float* __restrict__ bias,
    const void* __restrict__ res, int res_f32,
    void* __restrict__ C, int ldc, int K,
    int nM, int nN)
{
    __shared__ __bf16 lds[2][2][16384];   // [buf][A=0/B=1][slice*512 + lane*8]
    const int tid  = threadIdx.x;
    const int wave = tid >> 6, lane = tid & 63;
    const int quad = lane >> 4, l16 = lane & 15;
    const int wm = wave >> 2, wn = wave & 3;   // 2x4 wave grid

    // XCD swizzle: id%8 = XCD; each XCD owns nM/8 consecutive m-tiles.
    const int id  = blockIdx.x;
    const int xcd = id & 7;
    const int lid = id >> 3;
    const int mq  = lid / nN;
    const int mt  = xcd * (nM >> 3) + mq;
    const int nt  = lid - mq * nN;
    const int m0 = mt * 256, n0 = nt * 256;

    // per-thread global source offsets for the 4 A-slices / 4 B-slices this
    // wave stages: slice S = wave*4+j -> row (S>>1)*16+l16, k (S&1)*32+quad*8
    int aoff[4], boff[4];
    #pragma unroll
    for (int j = 0; j < 4; j++) {
        const int S = wave * 4 + j;
        const int row = (S >> 1) * 16 + l16;
        const int kof = (S & 1) * 32 + quad * 8;
        aoff[j] = (m0 + row) * lda + kof;
        boff[j] = (n0 + row) * ldb + kof;
    }

    // LDS byte-address bases (32-bit LDS address space) for asm ds_read.
    const uint32_t lds0 =
        (uint32_t)(uintptr_t)(__attribute__((address_space(3))) void*)&lds[0][0][0];
    const uint32_t aAd0 = lds0 + wm * 16384 + lane * 16;
    const uint32_t bAd0 = lds0 + 32768 + wn * 8192 + lane * 16;

    f32x4 acc[8][4] = {};
    bf16x8 rA[4][2], rB[4][2];

    const int ntk = K >> 6;

    // prologue: stage tile 0 -> buf0, tile 1 -> buf1; wait for tile 0 only.
    #pragma unroll
    for (int j = 0; j < 4; j++) {
        gld16(A  + aoff[j], &lds[0][0][(wave * 4 + j) * 512]);
        gld16(Bt + boff[j], &lds[0][1][(wave * 4 + j) * 512]);
    }
    #pragma unroll
    for (int j = 0; j < 4; j++) {
        gld16(A  + aoff[j] + 64, &lds[1][0][(wave * 4 + j) * 512]);
        gld16(Bt + boff[j] + 64, &lds[1][1][(wave * 4 + j) * 512]);
    }
    asm volatile("s_waitcnt vmcnt(8)");
    __builtin_amdgcn_s_barrier();

    for (int t = 0; t < ntk; ++t) {
        const int buf = t & 1;
        const uint32_t aAd = aAd0 + buf * 65536;
        const uint32_t bAd = bAd0 + buf * 65536;
        const bool pf = (t + 2 < ntk);
        const int kn = (t + 2) << 6;

        // ---- phase 0: ds_read A m0-3 + B n0-1; mfma m0-3 x n0-1
        DSR(rA[0][0], aAd, "0");    DSR(rA[0][1], aAd, "1024");
        DSR(rA[1][0], aAd, "2048"); DSR(rA[1][1], aAd, "3072");
        DSR(rA[2][0], aAd, "4096"); DSR(rA[2][1], aAd, "5120");
        DSR(rA[3][0], aAd, "6144"); DSR(rA[3][1], aAd, "7168");
        DSR(rB[0][0], bAd, "0");    DSR(rB[0][1], bAd, "1024");
        DSR(rB[1][0], bAd, "2048"); DSR(rB[1][1], bAd, "3072");
        __builtin_amdgcn_s_barrier();
        asm volatile("s_waitcnt lgkmcnt(0)");
        __builtin_amdgcn_sched_barrier(0);
        __builtin_amdgcn_s_setprio(1);
        #pragma unroll
        for (int i = 0; i < 4; i++)
            #pragma unroll
            for (int j = 0; j < 2; j++)
                #pragma unroll
                for (int ks = 0; ks < 2; ks++)
                    acc[i][j] = __builtin_amdgcn_mfma_f32_16x16x32_bf16(
                        rB[j][ks], rA[i][ks], acc[i][j], 0, 0, 0);
        __builtin_amdgcn_s_setprio(0);
        __builtin_amdgcn_s_barrier();

        // ---- phase 1: ds_read B n2-3; mfma m0-3 x n2-3
        DSR(rB[2][0], bAd, "4096"); DSR(rB[2][1], bAd, "5120");
        DSR(rB[3][0], bAd, "6144"); DSR(rB[3][1], bAd, "7168");
        __builtin_amdgcn_s_barrier();
        asm volatile("s_waitcnt lgkmcnt(0)");
        __builtin_amdgcn_sched_barrier(0);
        __builtin_amdgcn_s_setprio(1);
        #pragma unroll
        for (int i = 0; i < 4; i++)
            #pragma unroll
            for (int j = 2; j < 4; j++)
                #pragma unroll
                for (int ks = 0; ks < 2; ks++)
                    acc[i][j] = __builtin_amdgcn_mfma_f32_16x16x32_bf16(
                        rB[j][ks], rA[i][ks], acc[i][j], 0, 0, 0);
        __builtin_amdgcn_s_setprio(0);
        __builtin_amdgcn_s_barrier();

        // ---- phase 2: ds_read A m4-7; stage B(t+2) into this buf's B-half
        //      (B(t) fully consumed by P1's lgkmcnt(0))
        DSR(rA[0][0], aAd, "8192");  DSR(rA[0][1], aAd, "9216");
        DSR(rA[1][0], aAd, "10240"); DSR(rA[1][1], aAd, "11264");
        DSR(rA[2][0], aAd, "12288"); DSR(rA[2][1], aAd, "13312");
        DSR(rA[3][0], aAd, "14336"); DSR(rA[3][1], aAd, "15360");
        if (pf) {
            #pragma unroll
            for (int j = 0; j < 4; j++)
                gld16(Bt + boff[j] + kn, &lds[buf][1][(wave * 4 + j) * 512]);
        }
        __builtin_amdgcn_s_barrier();
        asm volatile("s_waitcnt lgkmcnt(0)");
        __builtin_amdgcn_sched_barrier(0);
        __builtin_amdgcn_s_setprio(1);
        #pragma unroll
        for (int i = 0; i < 4; i++)
            #pragma unroll
            for (int j = 0; j < 2; j++)
                #pragma unroll
                for (int ks = 0; ks < 2; ks++)
                    acc[4 + i][j] = __builtin_amdgcn_mfma_f32_16x16x32_bf16(
                        rB[j][ks], rA[i][ks], acc[4 + i][j], 0, 0, 0);
        __builtin_amdgcn_s_setprio(0);
        __builtin_amdgcn_s_barrier();

        // ---- phase 3: stage A(t+2) (A(t) consumed by P2's lgkmcnt(0));
        //      mfma m4-7 x n2-3; counted boundary wait
        if (pf) {
            #pragma unroll
            for (int j = 0; j < 4; j++)
                gld16(A + aoff[j] + kn, &lds[buf][0][(wave * 4 + j) * 512]);
        }
        __builtin_amdgcn_s_setprio(1);
        #pragma unroll
        for (int i = 0; i < 4; i++)
            #pragma unroll
            for (int j = 2; j < 4; j++)
                #pragma unroll
                for (int ks = 0; ks < 2; ks++)
                    acc[4 + i][j] = __builtin_amdgcn_mfma_f32_16x16x32_bf16(
                        rB[j][ks], rA[i][ks], acc[4 + i][j], 0, 0, 0);
        __builtin_amdgcn_s_setprio(0);
        // need A(t+1),B(t+1) landed; t+2's 8 loads may stay in flight.
        if (pf)                  asm volatile("s_waitcnt vmcnt(8)");
        else if (t + 1 < ntk)    asm volatile("s_waitcnt vmcnt(0)");
        __builtin_amdgcn_s_barrier();
    }

    // epilogue (swapped layout): lane(quad,l16) holds, for (i,j),
    // C[m0+wm*128+i*16+l16][n0+wn*64+j*16+quad*4 + r], r=0..3 consecutive.
    #pragma unroll
    for (int i = 0; i < 8; i++) {
        const int row = m0 + wm * 128 + i * 16 + l16;
        #pragma unroll
        for (int j = 0; j < 4; j++) {
            const int colb = n0 + wn * 64 + j * 16 + quad * 4;
            const size_t off = (size_t)row * ldc + colb;
            const f32x4 bv = *(const f32x4*)(bias + colb);
            f32x4 v;
            #pragma unroll
            for (int r = 0; r < 4; r++) v[r] = acc[i][j][r] + bv[r];
            if (MODE == 2) {
                #pragma unroll
                for (int r = 0; r < 4; r++)
                    v[r] = 0.5f * v[r] * (1.0f + erff(v[r] * 0.70710678118654752f));
            }
            if (MODE == 1) {
                if (res_f32) {
                    const f32x4 rv = *(const f32x4*)((const float*)res + off);
                    #pragma unroll
                    for (int r = 0; r < 4; r++) v[r] += rv[r];
                } else {
                    const bf16x4 rv = *(const bf16x4*)((const __bf16*)res + off);
                    #pragma unroll
                    for (int r = 0; r < 4; r++) v[r] += (float)rv[r];
                }
            }
            if (OUTF) {
                *(f32x4*)((float*)C + off) = v;
            } else {
                bf16x4 o;
                #pragma unroll
                for (int r = 0; r < 4; r++) o[r] = (__bf16)v[r];
                *(bf16x4*)((__bf16*)C + off) = o;
            }
        }
    }
}

// ---------------- fused QK^T * scale + rpb bias + softmax -> P -------------
// One block: 64 q-rows x full 256 k for one (window,head).  4 waves, each
// wave owns 16 q-rows (wave*16 + quad*4 + r), 16 col-blocks of 16.
__global__ __launch_bounds__(256) void qk_softmax(
    const __bf16* __restrict__ qkvb, const float* __restrict__ rpb,
    __bf16* __restrict__ Sc, int bh_base)
{
    __shared__ __align__(16) __bf16 Qs[64 * 72];
    __shared__ __align__(16) __bf16 Ks[256 * 72];
    __shared__ float rpbs[320];
    const int bhl = blockIdx.y;
    const int bh  = bh_base + bhl;
    const int bw = bh >> 3, head = bh & 7;
    const int m0 = blockIdx.x * 64;
    const int tid = threadIdx.x;
    const __bf16* qb = qkvb + (size_t)bw * WIN * 1536 + head * HD;

    {   // stage Q (64x64) and K (256x64), rows of 64 elems = 8 x bf16x8
        const int row = tid >> 3, l8 = (tid & 7) * 8;
        #pragma unroll
        for (int p = 0; p < 2; p++) {
            const int r = p * 32 + row;
            *(bf16x8*)(Qs + r * 72 + l8) =
                *(const bf16x8*)(qb + (size_t)(m0 + r) * 1536 + l8);
        }
        #pragma unroll
        for (int p = 0; p < 8; p++) {
            const int r = p * 32 + row;
            *(bf16x8*)(Ks + r * 72 + l8) =
                *(const bf16x8*)(qb + 512 + (size_t)r * 1536 + l8);
        }
        // rpb slice: bias(i,j) = rpb[i-j+255]; i-j+255-m0 in [0,318]
        rpbs[tid] = rpb[(size_t)(m0 + tid) * HEADS + head];
        if (tid < 63) rpbs[256 + tid] = rpb[(size_t)(m0 + 256 + tid) * HEADS + head];
    }
    __syncthreads();

    const int wave = tid >> 6, lane = tid & 63;
    const int quad = lane >> 4, l16 = lane & 15;
    bf16x8 af[2];
    #pragma unroll
    for (int ks = 0; ks < 2; ks++)
        af[ks] = *(const bf16x8*)(Qs + (wave * 16 + l16) * 72 + ks * 32 + quad * 8);

    f32x4 acc[16];
    #pragma unroll
    for (int nb = 0; nb < 16; nb++) acc[nb] = (f32x4){0.f, 0.f, 0.f, 0.f};
    #pragma unroll
    for (int nb = 0; nb < 16; nb++) {
        #pragma unroll
        for (int ks = 0; ks < 2; ks++) {
            bf16x8 bf = *(const bf16x8*)(Ks + (nb * 16 + l16) * 72 + ks * 32 + quad * 8);
            acc[nb] = __builtin_amdgcn_mfma_f32_16x16x32_bf16(af[ks], bf, acc[nb], 0, 0, 0);
        }
    }
    // scale + bias:  row li = wave*16+quad*4+r, col j = nb*16+l16
    #pragma unroll
    for (int nb = 0; nb < 16; nb++)
        #pragma unroll
        for (int r = 0; r < 4; r++) {
            const int li = wave * 16 + quad * 4 + r;
            acc[nb][r] = acc[nb][r] * 0.125f + rpbs[li - nb * 16 - l16 + 255];
        }
    // softmax per row r: reduce over nb (in-lane) then l16 (shfl within quad)
    __bf16* Sb = Sc + (size_t)bhl * (WIN * WIN);
    #pragma unroll
    for (int r = 0; r < 4; r++) {
        float m = -1e30f;
        #pragma unroll
        for (int nb = 0; nb < 16; nb++) m = fmaxf(m, acc[nb][r]);
        #pragma unroll
        for (int msk = 1; msk < 16; msk <<= 1) m = fmaxf(m, __shfl_xor(m, msk));
        float s = 0.f;
        #pragma unroll
        for (int nb = 0; nb < 16; nb++) { acc[nb][r] = __expf(acc[nb][r] - m); s += acc[nb][r]; }
        #pragma unroll
        for (int msk = 1; msk < 16; msk <<= 1) s += __shfl_xor(s, msk);
        const float inv = 1.0f / s;
        const int i = m0 + wave * 16 + quad * 4 + r;
        #pragma unroll
        for (int nb = 0; nb < 16; nb++)
            Sb[(size_t)i * WIN + nb * 16 + l16] = (__bf16)(acc[nb][r] * inv);
    }
}

// ---------------- 64x64 MFMA tile helper (pv) ------------------------------
__device__ __forceinline__ void mfma_tile64(
    const __bf16* __restrict__ A, int lda, int m0,
    const __bf16* __restrict__ Bt, int ldb, int n0,
    int K, f32x4* acc, __bf16* As, __bf16* Bs)
{
    const int tid  = threadIdx.x;
    const int wave = tid >> 6;
    const int lane = tid & 63;
    const int quad = lane >> 4;
    const int l16  = lane & 15;
    const int lrow = tid >> 2;          // 0..63
    const int lcol = (tid & 3) << 3;    // 0,8,16,24
    const __bf16* ap = A  + (size_t)(m0 + lrow) * lda + lcol;
    const __bf16* bp = Bt + (size_t)(n0 + lrow) * ldb + lcol;
    for (int k0 = 0; k0 < K; k0 += 32) {
        bf16x8 av = *(const bf16x8*)(ap + k0);
        bf16x8 bv = *(const bf16x8*)(bp + k0);
        __syncthreads();
        *(bf16x8*)(As + lrow * LDP + lcol) = av;
        *(bf16x8*)(Bs + lrow * LDP + lcol) = bv;
        __syncthreads();
        bf16x8 af = *(const bf16x8*)(As + (wave * 16 + l16) * LDP + (quad << 3));
        #pragma unroll
        for (int nb = 0; nb < 4; nb++) {
            bf16x8 bf = *(const bf16x8*)(Bs + (nb * 16 + l16) * LDP + (quad << 3));
            acc[nb] = __builtin_amdgcn_mfma_f32_16x16x32_bf16(af, bf, acc[nb], 0, 0, 0);
        }
    }
}

// ---------------- V^T per (window,head): Vt[d][j] = V[j][d] ----------------
__global__ __launch_bounds__(256) void vtrans(
    const __bf16* __restrict__ qkvb, __bf16* __restrict__ Vt, int bh_base)
{
    __shared__ __align__(16) __bf16 s[WIN * 72];
    const int bh = bh_base + blockIdx.x;
    const int bw = bh >> 3, head = bh & 7;
    const int tid = threadIdx.x;
    const __bf16* V = qkvb + (size_t)bw * WIN * 1536 + 1024 + head * HD;
    #pragma unroll
    for (int it = 0; it < 8; it++) {
        int idx = it * 256 + tid;
        int j = idx >> 3;
        int d0 = (idx & 7) * 8;
        *(bf16x8*)(s + j * 72 + d0) = *(const bf16x8*)(V + (size_t)j * 1536 + d0);
    }
    __syncthreads();
    __bf16* out = Vt + (size_t)blockIdx.x * (HD * WIN);
    #pragma unroll
    for (int it = 0; it < 8; it++) {
        int idx = it * 256 + tid;
        int d  = idx >> 5;
        int j0 = (idx & 31) * 8;
        bf16x8 v;
        #pragma unroll
        for (int j = 0; j < 8; j++) v[j] = s[(j0 + j) * 72 + d];
        *(bf16x8*)(out + (size_t)d * WIN + j0) = v;
    }
}

// ---------------- P@V -> attn_out ------------------------------------------
__global__ __launch_bounds__(256) void pv_gemm(
    const __bf16* __restrict__ Sc, const __bf16* __restrict__ Vt,
    __bf16* __restrict__ attnO, int bh_base)
{
    __shared__ __align__(16) __bf16 As[64 * LDP];
    __shared__ __align__(16) __bf16 Bs[64 * LDP];
    const int bhl = blockIdx.y;
    const int bh = bh_base + bhl;
    const int bw = bh >> 3, head = bh & 7;
    const int m0 = blockIdx.x * 64;
    const __bf16* P   = Sc + (size_t)bhl * (WIN * WIN);
    const __bf16* Vtb = Vt + (size_t)bhl * (HD * WIN);
    f32x4 acc[4] = {};
    mfma_tile64(P, WIN, m0, Vtb, WIN, 0, WIN, acc, As, Bs);
    const int lane = threadIdx.x & 63, wave = threadIdx.x >> 6;
    const int quad = lane >> 4, l16 = lane & 15;
    #pragma unroll
    for (int nb = 0; nb < 4; nb++) {
        const int d = nb * 16 + l16;
        #pragma unroll
        for (int r = 0; r < 4; r++) {
            const int i = m0 + wave * 16 + quad * 4 + r;
            attnO[(size_t)(bw * WIN + i) * DIMC + head * HD + d] = (__bf16)acc[nb][r];
        }
    }
}

// ---------------- LayerNorm: one wave per token ----------------------------
__global__ __launch_bounds__(256) void ln_kernel(
    const void* X, int xf,
    const float* __restrict__ g, const float* __restrict__ b,
    __bf16* O)
{
    const int tok  = blockIdx.x * 4 + (threadIdx.x >> 6);
    const int lane = threadIdx.x & 63;
    const size_t base = (size_t)tok * DIMC + lane * 8;
    float v[8];
    if (xf) {
        const float* xp = (const float*)X + base;
        f32x4 a = *(const f32x4*)xp;
        f32x4 c = *(const f32x4*)(xp + 4);
        #pragma unroll
        for (int j = 0; j < 4; j++) { v[j] = a[j]; v[4 + j] = c[j]; }
    } else {
        bf16x8 xv = *(const bf16x8*)((const __bf16*)X + base);
        #pragma unroll
        for (int j = 0; j < 8; j++) v[j] = (float)xv[j];
    }
    float s = 0.f, s2 = 0.f;
    #pragma unroll
    for (int j = 0; j < 8; j++) { s += v[j]; s2 += v[j] * v[j]; }
    #pragma unroll
    for (int off = 32; off; off >>= 1) { s += __shfl_xor(s, off); s2 += __shfl_xor(s2, off); }
    const float mean = s * (1.0f / DIMC);
    const float var  = s2 * (1.0f / DIMC) - mean * mean;
    const float rstd = rsqrtf(var + 1e-5f);
    f32x4 ga = *(const f32x4*)(g + lane * 8);
    f32x4 gc = *(const f32x4*)(g + lane * 8 + 4);
    f32x4 ba = *(const f32x4*)(b + lane * 8);
    f32x4 bc = *(const f32x4*)(b + lane * 8 + 4);
    bf16x8 ov;
    #pragma unroll
    for (int j = 0; j < 4; j++) {
        ov[j]     = (__bf16)((v[j]     - mean) * rstd * ga[j] + ba[j]);
        ov[4 + j] = (__bf16)((v[4 + j] - mean) * rstd * gc[j] + bc[j]);
    }
    *(bf16x8*)(O + base) = ov;
}

// ---------------- weight transpose+cast: fp32 KxN -> bf16 NxK --------------
__global__ __launch_bounds__(256) void wtrans(
    const float* __restrict__ W, __bf16* __restrict__ Wt, int K, int N)
{
    __shared__ __align__(16) __bf16 s[64 * 72];
    const int kb = blockIdx.y * 64, nb = blockIdx.x * 64;
    const int tid = threadIdx.x;
    #pragma unroll
    for (int it = 0; it < 2; it++) {
        int idx = it * 256 + tid;
        int lk = idx >> 3;
        int ln = (idx & 7) * 8;
        const float* wp = W + (size_t)(kb + lk) * N + nb + ln;
        f32x4 a = *(const f32x4*)wp;
        f32x4 c = *(const f32x4*)(wp + 4);
        bf16x8 v;
        #pragma unroll
        for (int j = 0; j < 4; j++) { v[j] = (__bf16)a[j]; v[4 + j] = (__bf16)c[j]; }
        *(bf16x8*)(s + lk * 72 + ln) = v;
    }
    __syncthreads();
    #pragma unroll
    for (int it = 0; it < 2; it++) {
        int idx = it * 256 + tid;
        int ln  = idx >> 3;
        int lkv = (idx & 7) * 8;
        bf16x8 v;
        #pragma unroll
        for (int j = 0; j < 8; j++) v[j] = s[(lkv + j) * 72 + ln];
        *(bf16x8*)(Wt + (size_t)(nb + ln) * K + kb + lkv) = v;
    }
}

// ---------------------------------------------------------------------------
extern "C" void kernel_launch(void* const* d_in, const int* in_sizes, int n_in,
                              void* d_out, int out_size, void* d_ws, size_t ws_size,
                              hipStream_t stream)
{
    const float* x      = (const float*)d_in[0];
    const float* n1g    = (const float*)d_in[1];
    const float* n1b    = (const float*)d_in[2];
    const float* qkv_w  = (const float*)d_in[3];
    const float* qkv_b  = (const float*)d_in[4];
    const float* rpb    = (const float*)d_in[5];
    const float* proj_w = (const float*)d_in[6];
    const float* proj_b = (const float*)d_in[7];
    const float* n2g    = (const float*)d_in[8];
    const float* n2b    = (const float*)d_in[9];
    const float* fc1_w  = (const float*)d_in[10];
    const float* fc1_b  = (const float*)d_in[11];
    const float* fc2_w  = (const float*)d_in[12];
    const float* fc2_b  = (const float*)d_in[13];
    float* out = (float*)d_out;

    // workspace layout (bytes), 216 MB peak; slots reused sequentially
    char* ws = (char*)d_ws;
    __bf16* qkvb  = (__bf16*)(ws + 0);
    __bf16* hid   = (__bf16*)(ws + 0);
    __bf16* h     = (__bf16*)(ws + 134217728);   // also Sc slot, also y/x2
    __bf16* Sc    = h;
    __bf16* y     = h;
    __bf16* attnO = (__bf16*)(ws + 167772160);
    __bf16* Vt    = (__bf16*)(ws + 201326592);
    __bf16* wq_t  = (__bf16*)(ws + 209715200);   // 1536x512
    __bf16* wp_t  = (__bf16*)(ws + 211288064);   // 512x512
    __bf16* w1_t  = (__bf16*)(ws + 211812352);   // 2048x512
    __bf16* w2_t  = (__bf16*)(ws + 213909504);   // 512x2048

    // 1) weight transposes (tiny)
    wtrans<<<dim3(1536 / 64, 512 / 64),  256, 0, stream>>>(qkv_w, wq_t, 512, 1536);
    wtrans<<<dim3(512 / 64,  512 / 64),  256, 0, stream>>>(proj_w, wp_t, 512, 512);
    wtrans<<<dim3(2048 / 64, 512 / 64),  256, 0, stream>>>(fc1_w, w1_t, 512, 2048);
    wtrans<<<dim3(512 / 64,  2048 / 64), 256, 0, stream>>>(fc2_w, w2_t, 2048, 512);

    // 2) LN1: h = LN(x)
    ln_kernel<<<NTOK / 4, 256, 0, stream>>>(x, 1, n1g, n1b, h);

    // 3) qkv = h @ qkv_w + qkv_b   (M=32768, N=1536, K=512); nM=128 nN=6
    gemm256<0, 0><<<768, 512, 0, stream>>>(
        h, DIMC, wq_t, DIMC, qkv_b, nullptr, 0, qkvb, 1536, DIMC, 128, 6);

    // 4) attention in 4 chunks of 256 (window,head) pairs
    for (int c = 0; c < 4; c++) {
        const int bh0 = c * 256;
        vtrans<<<256, 256, 0, stream>>>(qkvb, Vt, bh0);
        qk_softmax<<<dim3(4, 256), 256, 0, stream>>>(qkvb, rpb, Sc, bh0);
        pv_gemm<<<dim3(4, 256), 256, 0, stream>>>(Sc, Vt, attnO, bh0);
    }

    // 5) y = x + attnO @ proj_w + proj_b   (N=512, K=512); nM=128 nN=2
    gemm256<1, 0><<<256, 512, 0, stream>>>(
        attnO, DIMC, wp_t, DIMC, proj_b, x, 1, y, DIMC, DIMC, 128, 2);

    // 6) LN2 in place: x2 = LN(y)
    ln_kernel<<<NTOK / 4, 256, 0, stream>>>(y, 0, n2g, n2b, y);

    // 7) hid = gelu(x2 @ fc1_w + fc1_b)   (N=2048, K=512); nM=128 nN=8
    gemm256<2, 0><<<1024, 512, 0, stream>>>(
        y, DIMC, w1_t, DIMC, fc1_b, nullptr, 0, hid, HIDC, DIMC, 128, 8);

    // 8) out(fp32) = x2 + hid @ fc2_w + fc2_b  (N=512, K=2048); nM=128 nN=2
    gemm256<1, 1><<<256, 512, 0, stream>>>(
        hid, HIDC, w2_t, HIDC, fc2_b, y, 0, out, DIMC, HIDC, 128, 2);
}